// Round 6
// baseline (3194.351 us; speedup 1.0000x reference)
//
#include <hip/hip_runtime.h>

#define TT 1024
#define BB 64
#define FF 256
#define HH 512

// ---------------------------------------------------------------------------
// Kernel 1: i_n = x @ W_ih^T + b_ih   ->  written into io (= d_out), later
// overwritten in-place by the recurrence with h_t.  (unchanged)
// ---------------------------------------------------------------------------
__global__ __launch_bounds__(256) void in_gemm(
    const float* __restrict__ x, const float* __restrict__ Wih,
    const float* __restrict__ bih, float* __restrict__ io)
{
    __shared__ float xs[32][68];
    __shared__ float wst[64][68];

    const int bid = blockIdx.x;
    const int rb = bid >> 3, cb = bid & 7;
    const int m0 = rb * 32, n0 = cb * 64;
    const int t  = threadIdx.x;
    const int ti = t >> 4, tj = t & 15;

    float acc[2][4] = {{0.f,0.f,0.f,0.f},{0.f,0.f,0.f,0.f}};

    for (int k0 = 0; k0 < FF; k0 += 64) {
        {
            int flat = t * 8;
            int row = flat >> 6, col = flat & 63;
            const float* src = &x[(size_t)(m0 + row) * FF + k0 + col];
            float4 a = *(const float4*)&src[0];
            float4 b = *(const float4*)&src[4];
            *(float4*)&xs[row][col]     = a;
            *(float4*)&xs[row][col + 4] = b;
        }
        {
            int j  = t >> 2;
            int kk = (t & 3) * 16;
            const float* src = &Wih[(size_t)(n0 + j) * FF + k0 + kk];
            #pragma unroll
            for (int q = 0; q < 4; ++q) {
                float4 v = *(const float4*)&src[q * 4];
                wst[kk + q*4 + 0][j] = v.x;
                wst[kk + q*4 + 1][j] = v.y;
                wst[kk + q*4 + 2][j] = v.z;
                wst[kk + q*4 + 3][j] = v.w;
            }
        }
        __syncthreads();
        #pragma unroll
        for (int k = 0; k < 64; k += 4) {
            float4 xa = *(const float4*)&xs[ti][k];
            float4 xb = *(const float4*)&xs[ti + 16][k];
            #pragma unroll
            for (int q = 0; q < 4; ++q) {
                float4 wv = *(const float4*)&wst[k + q][tj * 4];
                float xav = (&xa.x)[q], xbv = (&xb.x)[q];
                acc[0][0] = fmaf(xav, wv.x, acc[0][0]);
                acc[0][1] = fmaf(xav, wv.y, acc[0][1]);
                acc[0][2] = fmaf(xav, wv.z, acc[0][2]);
                acc[0][3] = fmaf(xav, wv.w, acc[0][3]);
                acc[1][0] = fmaf(xbv, wv.x, acc[1][0]);
                acc[1][1] = fmaf(xbv, wv.y, acc[1][1]);
                acc[1][2] = fmaf(xbv, wv.z, acc[1][2]);
                acc[1][3] = fmaf(xbv, wv.w, acc[1][3]);
            }
        }
        __syncthreads();
    }

    float4 bv = *(const float4*)&bih[n0 + tj * 4];
    float4 r0 = make_float4(acc[0][0]+bv.x, acc[0][1]+bv.y, acc[0][2]+bv.z, acc[0][3]+bv.w);
    float4 r1 = make_float4(acc[1][0]+bv.x, acc[1][1]+bv.y, acc[1][2]+bv.z, acc[1][3]+bv.w);
    *(float4*)&io[(size_t)(m0 + ti)      * HH + n0 + tj * 4] = r0;
    *(float4*)&io[(size_t)(m0 + ti + 16) * HH + n0 + tj * 4] = r1;
}

// ---------------------------------------------------------------------------
// Kernel 2: persistent recurrence, ROUND-6 sync restructure.
//
// Rounds 2-5 post-mortem: step time ~6800 cy with only ~2300 cy of VALU
// issue -- the serial chain {store-drain -> barrier add -> spin -> h load}
// plus 4 __syncthreads dominated. W lives in the unified AGPR file
// (VGPR=84, no scratch HBM traffic) and is NOT the bottleneck.
//
// New protocol (exploits: wave w consumes exactly WG w's output rows):
//  * per-slice tags: WG s publishes h-slice, s_waitcnt vmcnt(0), then
//    tag[g][s] = t+1 (relaxed agent). No central barrier counter.
//  * wave w spins only on tag[g][w] >= t, loads its own 128 h floats,
//    stages its OWN LDS region -> no barrier needed for h staging.
//  * hprev kept in epilogue registers (no cross-wave LDS read).
//  * red[] parity-double-buffered -> ONE __syncthreads per step.
//    (red WAR 2 steps later is ordered via wave0's in-order epilogue ->
//     its arrival at the next step's barrier.)
//  * 2-deep h pipeline is safe: a WG writes h_{t+2} only after all 8 tags
//    >= t+1, which implies every group member finished READING h_t.
// ---------------------------------------------------------------------------
#define P8(A,i) "+v"(A[(i)+0]), "+v"(A[(i)+1]), "+v"(A[(i)+2]), "+v"(A[(i)+3]), \
                "+v"(A[(i)+4]), "+v"(A[(i)+5]), "+v"(A[(i)+6]), "+v"(A[(i)+7])

__global__ __launch_bounds__(512, 2) void mgu_rec(
    const float* __restrict__ Whh, const float* __restrict__ bhh,
    float* __restrict__ io, float* __restrict__ hbuf,
    unsigned int* __restrict__ bar)
{
    const int bid = blockIdx.x;
    const int s   = bid >> 5;     // row slice 0..7
    const int g   = bid & 31;     // batch group 0..31
    const int c0  = g * 2;        // first batch of this group
    const int tid = threadIdx.x;
    const int w   = tid >> 6;     // wave 0..7 -> 64-wide k-slice
    const int l   = tid & 63;     // lane

    __shared__ float hst[2][HH];        // [batch][k], per-wave-owned slices (4 KB)
    __shared__ float red[2][8][4][64];  // [parity][wave][pf0,pf1,pn0,pn1][lane] (16 KB)

    // --- persistent W (128 floats/thread; unified VGPR/AGPR file) ---
    float Wf[64], Wn[64];
    {
        const float* pf = &Whh[(size_t)(s * 64 + l) * HH + w * 64];
        const float* pn = &Whh[(size_t)(512 + s * 64 + l) * HH + w * 64];
        #pragma unroll
        for (int q = 0; q < 16; ++q) {
            float4 a = *(const float4*)&pf[q * 4];
            Wf[q*4+0] = a.x; Wf[q*4+1] = a.y; Wf[q*4+2] = a.z; Wf[q*4+3] = a.w;
            float4 b = *(const float4*)&pn[q * 4];
            Wn[q*4+0] = b.x; Wn[q*4+1] = b.y; Wn[q*4+2] = b.z; Wn[q*4+3] = b.w;
        }
    }
    // pins (constant indices only): forbid re-load from memory inside the loop
    asm volatile("" : P8(Wf,0),  P8(Wf,8),  P8(Wf,16), P8(Wf,24));
    asm volatile("" : P8(Wf,32), P8(Wf,40), P8(Wf,48), P8(Wf,56));
    asm volatile("" : P8(Wn,0),  P8(Wn,8),  P8(Wn,16), P8(Wn,24));
    asm volatile("" : P8(Wn,32), P8(Wn,40), P8(Wn,48), P8(Wn,56));

    // epilogue wave (wave 0): lane l handles row ej=l for BOTH batches
    float bfv = 0.f, bnv = 0.f;
    if (tid < 64) {
        bfv = bhh[s * 64 + l];
        bnv = bhh[512 + s * 64 + l];
    }
    float hprev0 = 0.f, hprev1 = 0.f;   // h_t at own rows, register-carried

    unsigned int* tagline = &bar[g * 32];  // 8 dwords used, 128B line per group

    for (int t = 0; t < TT; ++t) {
        const int p = t & 1;

        // prefetch i_n (independent of h) -- hidden under spin + FMA
        float in0 = 0.f, in1 = 0.f;
        size_t o0 = 0, o1 = 0;
        if (tid < 64) {
            o0 = ((size_t)t * BB + c0) * HH + s * 64 + l;
            o1 = o0 + HH;
            in0 = io[o0];
            in1 = io[o1];
        }

        // per-wave point-to-point wait: producer of our k-slice is WG w
        if (t > 0) {
            while (__hip_atomic_load(&tagline[w], __ATOMIC_RELAXED,
                                     __HIP_MEMORY_SCOPE_AGENT) < (unsigned)t) {
                __builtin_amdgcn_s_sleep(1);
            }
            asm volatile("" ::: "memory");  // no hoisting of h loads above spin
        }

        // load own h slice (2 batches x 64) from L3, stage to OWN LDS region
        {
            const float* b0 = &hbuf[p * BB * HH + (c0 + 0) * HH + w * 64 + l];
            const float* b1 = &hbuf[p * BB * HH + (c0 + 1) * HH + w * 64 + l];
            float v0 = __hip_atomic_load(b0, __ATOMIC_RELAXED, __HIP_MEMORY_SCOPE_AGENT);
            float v1 = __hip_atomic_load(b1, __ATOMIC_RELAXED, __HIP_MEMORY_SCOPE_AGENT);
            hst[0][w * 64 + l] = v0;
            hst[1][w * 64 + l] = v1;
        }
        // (compiler inserts lgkmcnt wait: wave reads only LDS it wrote)

        // partial dot products: 256 FMA/thread, h via LDS broadcast
        float pf0 = 0.f, pf1 = 0.f, pn0 = 0.f, pn1 = 0.f;
        #pragma unroll
        for (int q = 0; q < 16; ++q) {
            float4 h0 = *(const float4*)&hst[0][w * 64 + q * 4];
            float4 h1 = *(const float4*)&hst[1][w * 64 + q * 4];
            pf0 = fmaf(Wf[q*4+0], h0.x, pf0); pn0 = fmaf(Wn[q*4+0], h0.x, pn0);
            pf1 = fmaf(Wf[q*4+0], h1.x, pf1); pn1 = fmaf(Wn[q*4+0], h1.x, pn1);
            pf0 = fmaf(Wf[q*4+1], h0.y, pf0); pn0 = fmaf(Wn[q*4+1], h0.y, pn0);
            pf1 = fmaf(Wf[q*4+1], h1.y, pf1); pn1 = fmaf(Wn[q*4+1], h1.y, pn1);
            pf0 = fmaf(Wf[q*4+2], h0.z, pf0); pn0 = fmaf(Wn[q*4+2], h0.z, pn0);
            pf1 = fmaf(Wf[q*4+2], h1.z, pf1); pn1 = fmaf(Wn[q*4+2], h1.z, pn1);
            pf0 = fmaf(Wf[q*4+3], h0.w, pf0); pn0 = fmaf(Wn[q*4+3], h0.w, pn0);
            pf1 = fmaf(Wf[q*4+3], h1.w, pf1); pn1 = fmaf(Wn[q*4+3], h1.w, pn1);
            __builtin_amdgcn_sched_barrier(0);
        }
        red[p][w][0][l] = pf0; red[p][w][1][l] = pf1;
        red[p][w][2][l] = pn0; red[p][w][3][l] = pn1;

        __syncthreads();   // the ONLY intra-WG barrier per step (red ready)

        if (tid < 64) {
            float fs0 = 0.f, fs1 = 0.f, ns0 = 0.f, ns1 = 0.f;
            #pragma unroll
            for (int ww = 0; ww < 8; ++ww) {
                fs0 += red[p][ww][0][l]; fs1 += red[p][ww][1][l];
                ns0 += red[p][ww][2][l]; ns1 += red[p][ww][3][l];
            }
            float fg0 = 1.f / (1.f + expf(-(fs0 + bfv)));
            float nv0 = tanhf(in0 + fg0 * (ns0 + bnv));
            float hn0 = nv0 + (1.f - fg0) * (hprev0 - nv0);
            float fg1 = 1.f / (1.f + expf(-(fs1 + bfv)));
            float nv1 = tanhf(in1 + fg1 * (ns1 + bnv));
            float hn1 = nv1 + (1.f - fg1) * (hprev1 - nv1);
            hprev0 = hn0; hprev1 = hn1;

            // publish h first (critical path), io after
            float* d0 = &hbuf[(p ^ 1) * BB * HH + (c0 + 0) * HH + s * 64 + l];
            float* d1 = &hbuf[(p ^ 1) * BB * HH + (c0 + 1) * HH + s * 64 + l];
            __hip_atomic_store(d0, hn0, __ATOMIC_RELAXED, __HIP_MEMORY_SCOPE_AGENT);
            __hip_atomic_store(d1, hn1, __ATOMIC_RELAXED, __HIP_MEMORY_SCOPE_AGENT);
            io[o0] = hn0;
            io[o1] = hn1;

            // wave-level drain: all 4 stores at coherence point, then tag
            asm volatile("s_waitcnt vmcnt(0)" ::: "memory");
            if (tid == 0) {
                __hip_atomic_store(&tagline[s], (unsigned int)(t + 1),
                                   __ATOMIC_RELAXED, __HIP_MEMORY_SCOPE_AGENT);
            }
        }
        // no trailing barrier: hst slices are wave-private; red is
        // parity-buffered; waves 1..7 proceed straight to the next spin.
    }
}

// ---------------------------------------------------------------------------
extern "C" void kernel_launch(void* const* d_in, const int* in_sizes, int n_in,
                              void* d_out, int out_size, void* d_ws, size_t ws_size,
                              hipStream_t stream)
{
    const float* x   = (const float*)d_in[0];
    const float* Wih = (const float*)d_in[1];
    const float* Whh = (const float*)d_in[2];
    const float* bih = (const float*)d_in[3];
    const float* bhh = (const float*)d_in[4];
    float* io = (float*)d_out;

    float*        hbuf = (float*)d_ws;                                   // 2*64*512 f32 = 256 KB
    unsigned int* bar  = (unsigned int*)((char*)d_ws + 2 * BB * HH * 4); // 32 x 128B tag lines

    // zero h ping-pong (h0 = 0) and tags; re-runs every launch/replay.
    hipMemsetAsync(d_ws, 0, 2 * BB * HH * 4 + 32 * 128, stream);

    in_gemm<<<dim3(16384), dim3(256), 0, stream>>>(x, Wih, bih, io);
    mgu_rec<<<dim3(256), dim3(512), 0, stream>>>(Whh, bhh, io, hbuf, bar);
}

// Round 7
// 2667.335 us; speedup vs baseline: 1.1976x; 1.1976x over previous
//
#include <hip/hip_runtime.h>

#define TT 1024
#define BB 64
#define FF 256
#define HH 512

// ---------------------------------------------------------------------------
// Kernel 1: i_n = x @ W_ih^T + b_ih  -> io (= d_out), overwritten in-place by
// the recurrence with h_t.  (unchanged)
// ---------------------------------------------------------------------------
__global__ __launch_bounds__(256) void in_gemm(
    const float* __restrict__ x, const float* __restrict__ Wih,
    const float* __restrict__ bih, float* __restrict__ io)
{
    __shared__ float xs[32][68];
    __shared__ float wst[64][68];

    const int bid = blockIdx.x;
    const int rb = bid >> 3, cb = bid & 7;
    const int m0 = rb * 32, n0 = cb * 64;
    const int t  = threadIdx.x;
    const int ti = t >> 4, tj = t & 15;

    float acc[2][4] = {{0.f,0.f,0.f,0.f},{0.f,0.f,0.f,0.f}};

    for (int k0 = 0; k0 < FF; k0 += 64) {
        {
            int flat = t * 8;
            int row = flat >> 6, col = flat & 63;
            const float* src = &x[(size_t)(m0 + row) * FF + k0 + col];
            float4 a = *(const float4*)&src[0];
            float4 b = *(const float4*)&src[4];
            *(float4*)&xs[row][col]     = a;
            *(float4*)&xs[row][col + 4] = b;
        }
        {
            int j  = t >> 2;
            int kk = (t & 3) * 16;
            const float* src = &Wih[(size_t)(n0 + j) * FF + k0 + kk];
            #pragma unroll
            for (int q = 0; q < 4; ++q) {
                float4 v = *(const float4*)&src[q * 4];
                wst[kk + q*4 + 0][j] = v.x;
                wst[kk + q*4 + 1][j] = v.y;
                wst[kk + q*4 + 2][j] = v.z;
                wst[kk + q*4 + 3][j] = v.w;
            }
        }
        __syncthreads();
        #pragma unroll
        for (int k = 0; k < 64; k += 4) {
            float4 xa = *(const float4*)&xs[ti][k];
            float4 xb = *(const float4*)&xs[ti + 16][k];
            #pragma unroll
            for (int q = 0; q < 4; ++q) {
                float4 wv = *(const float4*)&wst[k + q][tj * 4];
                float xav = (&xa.x)[q], xbv = (&xb.x)[q];
                acc[0][0] = fmaf(xav, wv.x, acc[0][0]);
                acc[0][1] = fmaf(xav, wv.y, acc[0][1]);
                acc[0][2] = fmaf(xav, wv.z, acc[0][2]);
                acc[0][3] = fmaf(xav, wv.w, acc[0][3]);
                acc[1][0] = fmaf(xbv, wv.x, acc[1][0]);
                acc[1][1] = fmaf(xbv, wv.y, acc[1][1]);
                acc[1][2] = fmaf(xbv, wv.z, acc[1][2]);
                acc[1][3] = fmaf(xbv, wv.w, acc[1][3]);
            }
        }
        __syncthreads();
    }

    float4 bv = *(const float4*)&bih[n0 + tj * 4];
    float4 r0 = make_float4(acc[0][0]+bv.x, acc[0][1]+bv.y, acc[0][2]+bv.z, acc[0][3]+bv.w);
    float4 r1 = make_float4(acc[1][0]+bv.x, acc[1][1]+bv.y, acc[1][2]+bv.z, acc[1][3]+bv.w);
    *(float4*)&io[(size_t)(m0 + ti)      * HH + n0 + tj * 4] = r0;
    *(float4*)&io[(size_t)(m0 + ti + 16) * HH + n0 + tj * 4] = r1;
}

// ---------------------------------------------------------------------------
// Kernel 2: persistent recurrence, ROUND-7: epoch-in-mantissa data polling.
//
// Rounds 2-6 post-mortem: time invariant (~2.8 ms) across 3 W-handling
// schemes, 2 occupancy shapes, and a full sync restructure -> critical path
// is the serial 3x L3-RTT chain {h-store drain -> tag visible -> poll ->
// h load}. This round collapses it to ~1 RTT:
//  * h floats carry a 2-bit EPOCH in their low mantissa bits (rel err
//    ~5e-7, negligible). Consumers spin on the DATA itself: load own 128
//    floats, check all epoch bits current -> detection == data arrival.
//  * Producer: NO vmcnt drain, NO tag, NO fence. Stores flow to L3.
//  * 4-deep slot ring (t&3); epoch = (t>>2)%3+1 in {1,2,3}: memset zeros
//    (epoch 0) never match; slot-stale epochs from t-4/t-8 differ; >=12-step
//    skew impossible (each WG's step t transitively waits on all 8 WGs'
//    step t-1 => global skew <= 1).
//  * All h traffic relaxed AGENT atomics (sc1, L2-bypass both sides --
//    required: per-XCD L2s are not coherent).
// ---------------------------------------------------------------------------
#define P8(A,i) "+v"(A[(i)+0]), "+v"(A[(i)+1]), "+v"(A[(i)+2]), "+v"(A[(i)+3]), \
                "+v"(A[(i)+4]), "+v"(A[(i)+5]), "+v"(A[(i)+6]), "+v"(A[(i)+7])

__global__ __launch_bounds__(512, 2) void mgu_rec(
    const float* __restrict__ Whh, const float* __restrict__ bhh,
    float* __restrict__ io, float* __restrict__ hbuf)
{
    const int bid = blockIdx.x;
    const int s   = bid >> 5;     // row slice 0..7
    const int g   = bid & 31;     // batch group 0..31
    const int c0  = g * 2;        // first batch of this group
    const int tid = threadIdx.x;
    const int w   = tid >> 6;     // wave 0..7 -> 64-wide k-slice
    const int l   = tid & 63;     // lane

    __shared__ float hst[2][HH];        // [batch][k], wave-private slices (4 KB)
    __shared__ float red[2][8][4][64];  // [parity][wave][pf0,pf1,pn0,pn1][lane] (16 KB)

    // --- persistent W (128 floats/thread; unified VGPR/AGPR file) ---
    float Wf[64], Wn[64];
    {
        const float* pf = &Whh[(size_t)(s * 64 + l) * HH + w * 64];
        const float* pn = &Whh[(size_t)(512 + s * 64 + l) * HH + w * 64];
        #pragma unroll
        for (int q = 0; q < 16; ++q) {
            float4 a = *(const float4*)&pf[q * 4];
            Wf[q*4+0] = a.x; Wf[q*4+1] = a.y; Wf[q*4+2] = a.z; Wf[q*4+3] = a.w;
            float4 b = *(const float4*)&pn[q * 4];
            Wn[q*4+0] = b.x; Wn[q*4+1] = b.y; Wn[q*4+2] = b.z; Wn[q*4+3] = b.w;
        }
    }
    asm volatile("" : P8(Wf,0),  P8(Wf,8),  P8(Wf,16), P8(Wf,24));
    asm volatile("" : P8(Wf,32), P8(Wf,40), P8(Wf,48), P8(Wf,56));
    asm volatile("" : P8(Wn,0),  P8(Wn,8),  P8(Wn,16), P8(Wn,24));
    asm volatile("" : P8(Wn,32), P8(Wn,40), P8(Wn,48), P8(Wn,56));

    float bfv = 0.f, bnv = 0.f;
    if (tid < 64) {
        bfv = bhh[s * 64 + l];
        bnv = bhh[512 + s * 64 + l];
    }
    float hprev0 = 0.f, hprev1 = 0.f;   // clean h_t at own rows (registers)

    for (int t = 0; t < TT; ++t) {
        const int p = t & 1;

        // prefetch i_n (independent of h) -- hidden under the poll
        float in0 = 0.f, in1 = 0.f;
        size_t o0 = 0, o1 = 0;
        if (tid < 64) {
            o0 = ((size_t)t * BB + c0) * HH + s * 64 + l;
            o1 = o0 + HH;
            in0 = io[o0];
            in1 = io[o1];
        }

        // data-poll for own k-slice of h_{t-1}: detection == data arrival
        float v0, v1;
        if (t > 0) {
            const int tr      = t - 1;
            const int slot_r  = tr & 3;
            const unsigned ep = (unsigned)(((tr >> 2) % 3) + 1);
            const float* b0 = &hbuf[(size_t)slot_r * BB * HH
                                    + (size_t)c0 * HH + w * 64 + l];
            const float* b1 = b0 + HH;  // second batch
            for (;;) {
                v0 = __hip_atomic_load(b0, __ATOMIC_RELAXED, __HIP_MEMORY_SCOPE_AGENT);
                v1 = __hip_atomic_load(b1, __ATOMIC_RELAXED, __HIP_MEMORY_SCOPE_AGENT);
                bool ok = ((__float_as_uint(v0) & 3u) == ep) &&
                          ((__float_as_uint(v1) & 3u) == ep);
                if (__all(ok)) break;
            }
        } else {
            v0 = 0.f; v1 = 0.f;
        }
        hst[0][w * 64 + l] = v0;   // wave-private slice; no barrier needed
        hst[1][w * 64 + l] = v1;

        // partial dot products: 256 FMA/thread, h via LDS broadcast
        float pf0 = 0.f, pf1 = 0.f, pn0 = 0.f, pn1 = 0.f;
        #pragma unroll
        for (int q = 0; q < 16; ++q) {
            float4 h0 = *(const float4*)&hst[0][w * 64 + q * 4];
            float4 h1 = *(const float4*)&hst[1][w * 64 + q * 4];
            pf0 = fmaf(Wf[q*4+0], h0.x, pf0); pn0 = fmaf(Wn[q*4+0], h0.x, pn0);
            pf1 = fmaf(Wf[q*4+0], h1.x, pf1); pn1 = fmaf(Wn[q*4+0], h1.x, pn1);
            pf0 = fmaf(Wf[q*4+1], h0.y, pf0); pn0 = fmaf(Wn[q*4+1], h0.y, pn0);
            pf1 = fmaf(Wf[q*4+1], h1.y, pf1); pn1 = fmaf(Wn[q*4+1], h1.y, pn1);
            pf0 = fmaf(Wf[q*4+2], h0.z, pf0); pn0 = fmaf(Wn[q*4+2], h0.z, pn0);
            pf1 = fmaf(Wf[q*4+2], h1.z, pf1); pn1 = fmaf(Wn[q*4+2], h1.z, pn1);
            pf0 = fmaf(Wf[q*4+3], h0.w, pf0); pn0 = fmaf(Wn[q*4+3], h0.w, pn0);
            pf1 = fmaf(Wf[q*4+3], h1.w, pf1); pn1 = fmaf(Wn[q*4+3], h1.w, pn1);
            __builtin_amdgcn_sched_barrier(0);
        }
        red[p][w][0][l] = pf0; red[p][w][1][l] = pf1;
        red[p][w][2][l] = pn0; red[p][w][3][l] = pn1;

        __syncthreads();   // the only intra-WG barrier per step

        if (tid < 64) {
            float fs0 = 0.f, fs1 = 0.f, ns0 = 0.f, ns1 = 0.f;
            #pragma unroll
            for (int ww = 0; ww < 8; ++ww) {
                fs0 += red[p][ww][0][l]; fs1 += red[p][ww][1][l];
                ns0 += red[p][ww][2][l]; ns1 += red[p][ww][3][l];
            }
            float fg0 = 1.f / (1.f + expf(-(fs0 + bfv)));
            float nv0 = tanhf(in0 + fg0 * (ns0 + bnv));
            float hn0 = nv0 + (1.f - fg0) * (hprev0 - nv0);
            float fg1 = 1.f / (1.f + expf(-(fs1 + bfv)));
            float nv1 = tanhf(in1 + fg1 * (ns1 + bnv));
            float hn1 = nv1 + (1.f - fg1) * (hprev1 - nv1);
            hprev0 = hn0; hprev1 = hn1;

            // publish h FIRST (critical path): epoch-encoded, no drain/tag
            const int slot_w  = t & 3;
            const unsigned ep = (unsigned)(((t >> 2) % 3) + 1);
            float e0 = __uint_as_float((__float_as_uint(hn0) & ~3u) | ep);
            float e1 = __uint_as_float((__float_as_uint(hn1) & ~3u) | ep);
            float* d0 = &hbuf[(size_t)slot_w * BB * HH
                              + (size_t)c0 * HH + s * 64 + l];
            float* d1 = d0 + HH;
            __hip_atomic_store(d0, e0, __ATOMIC_RELAXED, __HIP_MEMORY_SCOPE_AGENT);
            __hip_atomic_store(d1, e1, __ATOMIC_RELAXED, __HIP_MEMORY_SCOPE_AGENT);

            // harness output (clean values), off the critical path
            io[o0] = hn0;
            io[o1] = hn1;
        }
        // no trailing barrier: hst is wave-private, red is parity-buffered
    }
}

// ---------------------------------------------------------------------------
extern "C" void kernel_launch(void* const* d_in, const int* in_sizes, int n_in,
                              void* d_out, int out_size, void* d_ws, size_t ws_size,
                              hipStream_t stream)
{
    const float* x   = (const float*)d_in[0];
    const float* Wih = (const float*)d_in[1];
    const float* Whh = (const float*)d_in[2];
    const float* bih = (const float*)d_in[3];
    const float* bhh = (const float*)d_in[4];
    float* io = (float*)d_out;

    float* hbuf = (float*)d_ws;   // 4 slots x 64 x 512 f32 = 512 KB

    // zero the slot ring: epoch bits become 0, which never matches the
    // live epochs {1,2,3}; re-runs every launch/replay -> deterministic.
    hipMemsetAsync(d_ws, 0, 4 * BB * HH * 4, stream);

    in_gemm<<<dim3(16384), dim3(256), 0, stream>>>(x, Wih, bih, io);
    mgu_rec<<<dim3(256), dim3(512), 0, stream>>>(Whh, bhh, io, hbuf);
}